// Round 12
// baseline (283.422 us; speedup 1.0000x reference)
//
#include <hip/hip_runtime.h>
#include <hip/hip_bf16.h>

#define DCH 64
#define NB_CSR 256          // edge-chunk blocks; chunk = ceil(e/256)
#define MAXBINS 256         // bins = ceil(n/256); n<=65536

typedef __attribute__((ext_vector_type(8))) short bfrag;   // 8 bf16
typedef __attribute__((ext_vector_type(4))) float ffrag;   // 4 fp32

static __device__ __forceinline__ unsigned short f2bf(float f) {
    unsigned u = __float_as_uint(f);
    unsigned r = (u + 0x7fffu + ((u >> 16) & 1u)) >> 16;   // RNE
    return (unsigned short)r;
}
static __device__ __forceinline__ float bf2f(unsigned short s) {
    return __uint_as_float(((unsigned)s) << 16);
}

// ---- CSR pass 1: per-block bin counts (bin = col>>8) ----
__global__ __launch_bounds__(1024) void binc_k(const int* __restrict__ col,
                                               unsigned* __restrict__ blkcnt, int e) {
    __shared__ unsigned bins[MAXBINS];
    int B = blockIdx.x, tid = threadIdx.x;
    int chunk = (e + NB_CSR - 1) / NB_CSR;
    int beg = B * chunk, end = min(e, beg + chunk);
    if (tid < MAXBINS) bins[tid] = 0;
    __syncthreads();
    for (int i = beg + tid; i < end; i += 1024)
        atomicAdd(&bins[col[i] >> 8], 1u);
    __syncthreads();
    if (tid < MAXBINS) blkcnt[B * MAXBINS + tid] = bins[tid];
}

// ---- CSR pass 2: block 0 = bin bases + cursors; block 1 = W pack ----
__global__ __launch_bounds__(256) void bincur_k(const unsigned* __restrict__ blkcnt,
                                                unsigned* __restrict__ blkcur,
                                                int* __restrict__ binbase,
                                                int* __restrict__ ptr,
                                                int nbins, int n, int e,
                                                const float* __restrict__ Ws,
                                                short* __restrict__ wpk, int L) {
    if (blockIdx.x == 1) {                       // W pack (independent work)
        for (int ent = threadIdx.x; ent < L * 512; ent += 256) {
            int layer = ent >> 9;
            int r = ent & 511;
            int lane = r & 63;
            int st = r >> 6;
            int s = st >> 2, t = st & 3;
            int quad = lane >> 4;
            int ncol = t * 16 + (lane & 15);
            const float* W = Ws + (size_t)layer * DCH * DCH;
            union { short sh[8]; int4 v; } hi, lo;
#pragma unroll
            for (int j = 0; j < 8; ++j) {
                int k = s * 32 + quad * 8 + j;
                float w = W[k * DCH + ncol];
                unsigned short h = f2bf(w);
                hi.sh[j] = (short)h;
                lo.sh[j] = (short)f2bf(w - bf2f(h));
            }
            *(int4*)(wpk + ((size_t)(layer * 2 + 0) * 512 + r) * 8) = hi.v;
            *(int4*)(wpk + ((size_t)(layer * 2 + 1) * 512 + r) * 8) = lo.v;
        }
        return;
    }
    __shared__ unsigned tot[MAXBINS];
    __shared__ unsigned base[MAXBINS + 1];
    int j = threadIdx.x;
    unsigned t = 0;
    if (j < nbins) {
        for (int B = 0; B < NB_CSR; B += 8) {
            t += blkcnt[(B + 0) * MAXBINS + j] + blkcnt[(B + 1) * MAXBINS + j]
               + blkcnt[(B + 2) * MAXBINS + j] + blkcnt[(B + 3) * MAXBINS + j]
               + blkcnt[(B + 4) * MAXBINS + j] + blkcnt[(B + 5) * MAXBINS + j]
               + blkcnt[(B + 6) * MAXBINS + j] + blkcnt[(B + 7) * MAXBINS + j];
        }
    }
    tot[j] = t;
    __syncthreads();
    if (j == 0) {
        unsigned run = 0;
        for (int k = 0; k < nbins; ++k) { base[k] = run; run += tot[k]; }
        base[nbins] = run;
    }
    __syncthreads();
    if (j < nbins) {
        unsigned run = base[j];
        binbase[j] = (int)run;
        for (int B = 0; B < NB_CSR; B += 4) {
            unsigned c0 = blkcnt[(B + 0) * MAXBINS + j];
            unsigned c1 = blkcnt[(B + 1) * MAXBINS + j];
            unsigned c2 = blkcnt[(B + 2) * MAXBINS + j];
            unsigned c3 = blkcnt[(B + 3) * MAXBINS + j];
            blkcur[(B + 0) * MAXBINS + j] = run;  run += c0;
            blkcur[(B + 1) * MAXBINS + j] = run;  run += c1;
            blkcur[(B + 2) * MAXBINS + j] = run;  run += c2;
            blkcur[(B + 3) * MAXBINS + j] = run;  run += c3;
        }
    }
    if (j == 0) { binbase[nbins] = e; ptr[n] = e; }
}

// ---- CSR pass 3: scatter packed records to bins ----
__global__ __launch_bounds__(1024) void binfill_k(const int* __restrict__ row,
                                                  const int* __restrict__ col,
                                                  const float* __restrict__ ew,
                                                  const unsigned* __restrict__ blkcur,
                                                  uint2* __restrict__ rec, int e) {
    __shared__ unsigned cur[MAXBINS];
    int B = blockIdx.x, tid = threadIdx.x;
    int chunk = (e + NB_CSR - 1) / NB_CSR;
    int beg = B * chunk, end = min(e, beg + chunk);
    if (tid < MAXBINS) cur[tid] = blkcur[B * MAXBINS + tid];
    __syncthreads();
    for (int i = beg + tid; i < end; i += 1024) {
        int c = col[i];
        unsigned slot = atomicAdd(&cur[c >> 8], 1u);
        rec[slot] = make_uint2((unsigned)row[i] | ((unsigned)(c & 255) << 20),
                               __float_as_uint(ew[i]));
    }
}

// ---- CSR pass 4: node hist + ptr + fused deg/dis + placement ----
__global__ __launch_bounds__(1024) void csr_k(const uint2* __restrict__ rec,
                                              const int* __restrict__ binbase,
                                              int* __restrict__ ptr,
                                              uint2* __restrict__ edg,
                                              float* __restrict__ dis, int n) {
    __shared__ unsigned ncnt[256];
    __shared__ unsigned nbase[256];
    __shared__ float degs[256];
    int b = blockIdx.x, tid = threadIdx.x;
    int beg = binbase[b], end = binbase[b + 1];
    int node0 = b << 8;
    int nn = min(256, n - node0);
    if (tid < 256) { ncnt[tid] = 0; degs[tid] = 0.f; }
    __syncthreads();
    for (int i = beg + tid; i < end; i += 1024) {
        uint2 r = rec[i];
        unsigned c8 = r.x >> 20;
        atomicAdd(&ncnt[c8], 1u);
        atomicAdd(&degs[c8], __uint_as_float(r.y));
    }
    __syncthreads();
    if (tid == 0) {
        unsigned run = (unsigned)beg;
        for (int k = 0; k < 256; ++k) { nbase[k] = run; run += ncnt[k]; }
    }
    __syncthreads();
    if (tid < nn) {
        ptr[node0 + tid] = (int)nbase[tid];
        dis[node0 + tid] = rsqrtf(degs[tid] + 2.0f);
    }
    if (tid < 256) ncnt[tid] = 0;
    __syncthreads();
    for (int i = beg + tid; i < end; i += 1024) {
        uint2 r = rec[i];
        unsigned c8 = r.x >> 20;
        unsigned pos = nbase[c8] + atomicAdd(&ncnt[c8], 1u);
        edg[pos] = make_uint2(r.x & 0xFFFFFu, r.y);
    }
}

// edg.y <- w * dis[src]
__global__ __launch_bounds__(256) void normw_k(uint2* __restrict__ edg,
                                               const float* __restrict__ dis, int e) {
    int i = blockIdx.x * 256 + threadIdx.x;
    if (i >= e) return;
    uint2 ev = edg[i];
    ((unsigned*)edg)[2 * i + 1] =
        __float_as_uint(__uint_as_float(ev.y) * dis[ev.x]);
}

// layer-0 GEMM from fp32 x0 (bf16-split MFMA); writes h as TWO channel planes
// (plane s = channels 32s..32s+31, [n][32] bf16) so gather footprint/plane = 3.2MB.
__global__ __launch_bounds__(256) void gemm0_k(const float* __restrict__ x,
                                               const short* __restrict__ wpk_layer,
                                               unsigned short* __restrict__ hb,
                                               int n, int n_tiles) {
    __shared__ short Wl[2][512 * 8];
    {
        const int4* src = (const int4*)wpk_layer;
        int4* dst = (int4*)&Wl[0][0];
        for (int i = threadIdx.x; i < 1024; i += 256) dst[i] = src[i];
    }
    __syncthreads();
    int wave = threadIdx.x >> 6, lane = threadIdx.x & 63;
    int tile = blockIdx.x * 4 + wave;
    if (tile >= n_tiles) return;
    int m = lane & 15, quad = lane >> 4;
    int row = tile * 16 + m;
    size_t nstride = (size_t)n * 32;

    float av[2][8];
    {
        const float4* p0 = (const float4*)(x + (size_t)row * DCH + quad * 8);
        const float4* p1 = (const float4*)(x + (size_t)row * DCH + 32 + quad * 8);
        float4 a0 = p0[0], a1 = p0[1], b0 = p1[0], b1 = p1[1];
        av[0][0] = a0.x; av[0][1] = a0.y; av[0][2] = a0.z; av[0][3] = a0.w;
        av[0][4] = a1.x; av[0][5] = a1.y; av[0][6] = a1.z; av[0][7] = a1.w;
        av[1][0] = b0.x; av[1][1] = b0.y; av[1][2] = b0.z; av[1][3] = b0.w;
        av[1][4] = b1.x; av[1][5] = b1.y; av[1][6] = b1.z; av[1][7] = b1.w;
    }
    bfrag ah[2], al[2];
#pragma unroll
    for (int s = 0; s < 2; ++s)
#pragma unroll
        for (int j = 0; j < 8; ++j) {
            unsigned short hbv = f2bf(av[s][j]);
            ah[s][j] = (short)hbv;
            al[s][j] = (short)f2bf(av[s][j] - bf2f(hbv));
        }

#pragma unroll
    for (int t = 0; t < 4; ++t) {
        ffrag acc = {0.f, 0.f, 0.f, 0.f};
#pragma unroll
        for (int s = 0; s < 2; ++s) {
            bfrag wh = *(bfrag*)&Wl[0][((s * 4 + t) * 64 + lane) * 8];
            bfrag wl = *(bfrag*)&Wl[1][((s * 4 + t) * 64 + lane) * 8];
            acc = __builtin_amdgcn_mfma_f32_16x16x32_bf16(ah[s], wh, acc, 0, 0, 0);
            acc = __builtin_amdgcn_mfma_f32_16x16x32_bf16(al[s], wh, acc, 0, 0, 0);
            acc = __builtin_amdgcn_mfma_f32_16x16x32_bf16(ah[s], wl, acc, 0, 0, 0);
        }
        int colc = t * 16 + m;
        int pl = colc >> 5, c31 = colc & 31;
#pragma unroll
        for (int r = 0; r < 4; ++r)
            hb[pl * nstride + (size_t)(tile * 16 + quad * 4 + r) * 32 + c31] = f2bf(acc[r]);
    }
}

// gather-half: grid.y = plane s (3.2MB L2-resident footprint per plane; flat
// dispatch order separates planes temporally). Wave = node (4 serial/wave).
// 16 lanes/edge (lane p16 = channel pair), 4 edges/step, 8-deep pipeline.
// mode 0: write activation half as bf16 hi/lo planes (fp32-equivalent).
// mode 1 (last layer): dot with Wf half, emit partial[node*2+s].
__global__ __launch_bounds__(256) void gh_k(const int* __restrict__ ptr,
                                            const uint2* __restrict__ edg,
                                            const float* __restrict__ dis,
                                            const unsigned short* __restrict__ hplane,
                                            const float* __restrict__ b,
                                            const float* __restrict__ Wf,
                                            unsigned short* __restrict__ xhi,
                                            unsigned short* __restrict__ xlo,
                                            float* __restrict__ partial,
                                            int n, int mode) {
    int s = blockIdx.y;
    size_t nstride = (size_t)n * 32;
    const unsigned short* hp = hplane + s * nstride;
    int w = threadIdx.x >> 6, lane = threadIdx.x & 63;
    int p16 = lane & 15, grp = lane >> 4;
    int nd0 = blockIdx.x * 16 + w * 4;
    if (nd0 >= n) return;
    int bg[4], en[4]; float dc[4];
#pragma unroll
    for (int i = 0; i < 4; ++i) {                // header preload (independent loads)
        int nd = min(nd0 + i, n - 1);
        bg[i] = ptr[nd]; en[i] = ptr[nd + 1]; dc[i] = dis[nd];
    }
    const unsigned long long* e8 = (const unsigned long long*)edg;
    float2 bv = ((const float2*)b)[s * 16 + p16];
    float2 wv = ((const float2*)Wf)[s * 16 + p16];
#pragma unroll 1
    for (int i = 0; i < 4; ++i) {
        int node = nd0 + i;
        if (node >= n) break;
        float dis_c = dc[i];
        float a0 = 0.f, a1 = 0.f;
        if (grp == 0) {                          // self-loop term (once)
            unsigned sv = *(const unsigned*)(hp + (size_t)node * 32 + 2 * p16);
            a0 = 2.0f * dis_c * __uint_as_float(sv << 16);
            a1 = 2.0f * dis_c * __uint_as_float(sv & 0xffff0000u);
        }
        for (int base = bg[i]; base < en[i]; base += 64) {
            int idx = base + lane;
            unsigned long long ev = (idx < en[i])
                ? __builtin_nontemporal_load(e8 + idx) : 0ull;   // nt: don't evict hp
            int rv = (int)(unsigned)ev;
            float nv = __uint_as_float((unsigned)(ev >> 32));    // pre-folded w*dis[src]
            int m = min(64, en[i] - base);
            int ns8 = (((m + 3) >> 2) + 7) & ~7;
            for (int j0 = 0; j0 < ns8; j0 += 8) {
                unsigned hv[8]; float nn[8];
#pragma unroll
                for (int q = 0; q < 8; ++q) {
                    int eidx = (j0 + q) * 4 + grp;
                    int r = __shfl(rv, eidx);
                    nn[q] = __shfl(nv, eidx);    // padded lanes carry nv=0
                    hv[q] = *(const unsigned*)(hp + (size_t)r * 32 + 2 * p16);
                }
#pragma unroll
                for (int q = 0; q < 8; ++q) {
                    a0 += __uint_as_float(hv[q] << 16) * nn[q];
                    a1 += __uint_as_float(hv[q] & 0xffff0000u) * nn[q];
                }
            }
        }
        a0 += __shfl_xor(a0, 16); a0 += __shfl_xor(a0, 32);
        a1 += __shfl_xor(a1, 16); a1 += __shfl_xor(a1, 32);
        float x0 = fmaxf(dis_c * a0 + bv.x, 0.f);
        float x1 = fmaxf(dis_c * a1 + bv.y, 0.f);
        if (mode == 0) {
            if (grp == 0) {
                unsigned short h0 = f2bf(x0), h1 = f2bf(x1);
                unsigned short l0 = f2bf(x0 - bf2f(h0)), l1 = f2bf(x1 - bf2f(h1));
                *(unsigned*)(xhi + s * nstride + (size_t)node * 32 + 2 * p16) =
                    (unsigned)h0 | ((unsigned)h1 << 16);
                *(unsigned*)(xlo + s * nstride + (size_t)node * 32 + 2 * p16) =
                    (unsigned)l0 | ((unsigned)l1 << 16);
            }
        } else {
            float v = x0 * wv.x + x1 * wv.y;
            v += __shfl_down(v, 8); v += __shfl_down(v, 4);
            v += __shfl_down(v, 2); v += __shfl_down(v, 1);
            if (lane == 0) partial[2 * node + s] = v;
        }
    }
}

// mid-layer GEMM: A-fragments read DIRECTLY as bf16 hi/lo planes (no staging,
// no conversion); writes next h planes.
__global__ __launch_bounds__(256) void gemmn_k(const unsigned short* __restrict__ xhi,
                                               const unsigned short* __restrict__ xlo,
                                               const short* __restrict__ wpk_layer,
                                               unsigned short* __restrict__ hb,
                                               int n, int n_tiles) {
    __shared__ short Wl[2][512 * 8];
    {
        const int4* src = (const int4*)wpk_layer;
        int4* dst = (int4*)&Wl[0][0];
        for (int i = threadIdx.x; i < 1024; i += 256) dst[i] = src[i];
    }
    __syncthreads();
    int wave = threadIdx.x >> 6, lane = threadIdx.x & 63;
    int tile = blockIdx.x * 4 + wave;
    if (tile >= n_tiles) return;
    int m = lane & 15, quad = lane >> 4;
    int row = tile * 16 + m;
    size_t nstride = (size_t)n * 32;
    bfrag ah[2], al[2];
#pragma unroll
    for (int s = 0; s < 2; ++s) {
        ah[s] = *(const bfrag*)(xhi + s * nstride + (size_t)row * 32 + quad * 8);
        al[s] = *(const bfrag*)(xlo + s * nstride + (size_t)row * 32 + quad * 8);
    }
#pragma unroll
    for (int t = 0; t < 4; ++t) {
        ffrag acc = {0.f, 0.f, 0.f, 0.f};
#pragma unroll
        for (int s = 0; s < 2; ++s) {
            bfrag wh = *(bfrag*)&Wl[0][((s * 4 + t) * 64 + lane) * 8];
            bfrag wl = *(bfrag*)&Wl[1][((s * 4 + t) * 64 + lane) * 8];
            acc = __builtin_amdgcn_mfma_f32_16x16x32_bf16(ah[s], wh, acc, 0, 0, 0);
            acc = __builtin_amdgcn_mfma_f32_16x16x32_bf16(al[s], wh, acc, 0, 0, 0);
            acc = __builtin_amdgcn_mfma_f32_16x16x32_bf16(ah[s], wl, acc, 0, 0, 0);
        }
        int colc = t * 16 + m;
        int pl = colc >> 5, c31 = colc & 31;
#pragma unroll
        for (int r = 0; r < 4; ++r)
            hb[pl * nstride + (size_t)(tile * 16 + quad * 4 + r) * 32 + c31] = f2bf(acc[r]);
    }
}

// out[i] = partial[2i] + partial[2i+1] + bf
__global__ __launch_bounds__(256) void fsum_k(const float* __restrict__ partial,
                                              const float* __restrict__ bf,
                                              float* __restrict__ out, int n) {
    int i = blockIdx.x * 256 + threadIdx.x;
    if (i < n) out[i] = partial[2 * i] + partial[2 * i + 1] + bf[0];
}

extern "C" void kernel_launch(void* const* d_in, const int* in_sizes, int n_in,
                              void* d_out, int out_size, void* d_ws, size_t ws_size,
                              hipStream_t stream) {
    const float* x0 = (const float*)d_in[0];
    const int*   ei = (const int*)d_in[1];
    const float* ew = (const float*)d_in[2];
    const float* Ws = (const float*)d_in[3];
    const float* bs = (const float*)d_in[4];
    const float* Wf = (const float*)d_in[5];
    const float* bf = (const float*)d_in[6];

    const int n = in_sizes[0] / DCH;
    const int e = in_sizes[2];
    const int L = in_sizes[3] / (DCH * DCH);     // = 3

    const int* row = ei;        // edge_index[0] = source (gathered)
    const int* col = ei + e;    // edge_index[1] = target (aggregated)
    const int nbins = (n + 255) >> 8;            // <= 256

    size_t off = 0;
    auto alloc = [&](size_t bytes) {
        off = (off + 255) & ~(size_t)255;
        void* r = (char*)d_ws + off;
        off += bytes;
        return r;
    };
    const size_t nstride = (size_t)n * 32;
    int*      ptr     = (int*)     alloc((size_t)(n + 1) * 4);
    float*    dis     = (float*)   alloc((size_t)n * 4);
    float*    partial = (float*)   alloc((size_t)n * 2 * 4);
    short*    wpk     = (short*)   alloc((size_t)L * 2 * 512 * 8 * 2);
    uint2*    edg     = (uint2*)   alloc((size_t)e * 8);
    unsigned* blkcnt  = (unsigned*)alloc((size_t)NB_CSR * MAXBINS * 4);
    unsigned* blkcur  = (unsigned*)alloc((size_t)NB_CSR * MAXBINS * 4);
    int*      binbase = (int*)     alloc((size_t)(MAXBINS + 1) * 4);
    // region A: rec (e uint2 = 10 MB) aliases x planes (4*nstride u16 = 12.8 MB);
    // rec dead after csr_k; x planes first written by gh_k (later in stream).
    size_t szR = (size_t)e * 8, szX = 4 * nstride * 2;
    unsigned char* regA = (unsigned char*)alloc(szR > szX ? szR : szX);
    uint2* rec = (uint2*)regA;
    unsigned short* xhi = (unsigned short*)regA;           // planes s=0,1
    unsigned short* xlo = xhi + 2 * nstride;               // planes s=0,1
    unsigned short* hb  = (unsigned short*)alloc(2 * nstride * 2);  // h planes (reused all layers)

    dim3 blk(256);
    const int n_tiles = (n + 15) / 16;
    const dim3 gh_grid((n + 15) / 16, 2);

    // ---- CSR build (bin sort; pack rides in bincur block 1) ----
    binc_k   <<<dim3(NB_CSR), dim3(1024), 0, stream>>>(col, blkcnt, e);
    bincur_k <<<dim3(2), blk, 0, stream>>>(blkcnt, blkcur, binbase, ptr, nbins, n, e, Ws, wpk, L);
    binfill_k<<<dim3(NB_CSR), dim3(1024), 0, stream>>>(row, col, ew, blkcur, rec, e);
    csr_k    <<<dim3(nbins), dim3(1024), 0, stream>>>(rec, binbase, ptr, edg, dis, n);
    normw_k  <<<dim3((e + 255) / 256), blk, 0, stream>>>(edg, dis, e);

    // ---- layers ----
    const size_t wstride = (size_t)2 * 512 * 8;
    gemm0_k<<<dim3((n_tiles + 3) / 4), blk, 0, stream>>>(x0, wpk, hb, n, n_tiles);
    gh_k   <<<gh_grid, blk, 0, stream>>>(ptr, edg, dis, hb, bs, Wf,
                                         xhi, xlo, partial, n, 0);
    gemmn_k<<<dim3((n_tiles + 3) / 4), blk, 0, stream>>>(xhi, xlo, wpk + wstride, hb, n, n_tiles);
    gh_k   <<<gh_grid, blk, 0, stream>>>(ptr, edg, dis, hb, bs + DCH, Wf,
                                         xhi, xlo, partial, n, 0);
    gemmn_k<<<dim3((n_tiles + 3) / 4), blk, 0, stream>>>(xhi, xlo, wpk + 2 * wstride, hb, n, n_tiles);
    gh_k   <<<gh_grid, blk, 0, stream>>>(ptr, edg, dis, hb, bs + 2 * DCH, Wf,
                                         xhi, xlo, partial, n, 1);
    fsum_k <<<dim3((n + 255) / 256), blk, 0, stream>>>(partial, bf, (float*)d_out, n);
}

// Round 13
// 222.308 us; speedup vs baseline: 1.2749x; 1.2749x over previous
//
#include <hip/hip_runtime.h>
#include <hip/hip_bf16.h>

#define DCH 64
#define NB_CSR 256          // edge-chunk blocks; chunk = ceil(e/256)
#define MAXBINS 256         // bins = ceil(n/256); n<=65536

typedef __attribute__((ext_vector_type(8))) short bfrag;   // 8 bf16
typedef __attribute__((ext_vector_type(4))) float ffrag;   // 4 fp32

static __device__ __forceinline__ unsigned short f2bf(float f) {
    unsigned u = __float_as_uint(f);
    unsigned r = (u + 0x7fffu + ((u >> 16) & 1u)) >> 16;   // RNE
    return (unsigned short)r;
}
static __device__ __forceinline__ float bf2f(unsigned short s) {
    return __uint_as_float(((unsigned)s) << 16);
}

// ---- CSR pass 1: per-block bin counts (bin = col>>8) ----
__global__ __launch_bounds__(1024) void binc_k(const int* __restrict__ col,
                                               unsigned* __restrict__ blkcnt, int e) {
    __shared__ unsigned bins[MAXBINS];
    int B = blockIdx.x, tid = threadIdx.x;
    int chunk = (e + NB_CSR - 1) / NB_CSR;
    int beg = B * chunk, end = min(e, beg + chunk);
    if (tid < MAXBINS) bins[tid] = 0;
    __syncthreads();
    for (int i = beg + tid; i < end; i += 1024)
        atomicAdd(&bins[col[i] >> 8], 1u);
    __syncthreads();
    if (tid < MAXBINS) blkcnt[B * MAXBINS + tid] = bins[tid];
}

// ---- CSR pass 2 (1 block): bin bases + per-(block,bin) cursors ----
__global__ __launch_bounds__(256) void bincur_k(const unsigned* __restrict__ blkcnt,
                                                unsigned* __restrict__ blkcur,
                                                int* __restrict__ binbase,
                                                int* __restrict__ ptr,
                                                int nbins, int n, int e) {
    __shared__ unsigned tot[MAXBINS];
    __shared__ unsigned base[MAXBINS + 1];
    int j = threadIdx.x;
    unsigned t = 0;
    if (j < nbins) {
        for (int B = 0; B < NB_CSR; B += 8) {      // 8-deep MLP column sum
            t += blkcnt[(B + 0) * MAXBINS + j] + blkcnt[(B + 1) * MAXBINS + j]
               + blkcnt[(B + 2) * MAXBINS + j] + blkcnt[(B + 3) * MAXBINS + j]
               + blkcnt[(B + 4) * MAXBINS + j] + blkcnt[(B + 5) * MAXBINS + j]
               + blkcnt[(B + 6) * MAXBINS + j] + blkcnt[(B + 7) * MAXBINS + j];
        }
    }
    tot[j] = t;
    __syncthreads();
    if (j == 0) {
        unsigned run = 0;
        for (int k = 0; k < nbins; ++k) { base[k] = run; run += tot[k]; }
        base[nbins] = run;
    }
    __syncthreads();
    if (j < nbins) {
        unsigned run = base[j];
        binbase[j] = (int)run;
        for (int B = 0; B < NB_CSR; B += 4) {      // 4-deep MLP walk
            unsigned c0 = blkcnt[(B + 0) * MAXBINS + j];
            unsigned c1 = blkcnt[(B + 1) * MAXBINS + j];
            unsigned c2 = blkcnt[(B + 2) * MAXBINS + j];
            unsigned c3 = blkcnt[(B + 3) * MAXBINS + j];
            blkcur[(B + 0) * MAXBINS + j] = run;  run += c0;
            blkcur[(B + 1) * MAXBINS + j] = run;  run += c1;
            blkcur[(B + 2) * MAXBINS + j] = run;  run += c2;
            blkcur[(B + 3) * MAXBINS + j] = run;  run += c3;
        }
    }
    if (j == 0) { binbase[nbins] = e; ptr[n] = e; }
}

// ---- CSR pass 3: scatter packed records to bins (runs at block cursors) ----
__global__ __launch_bounds__(1024) void binfill_k(const int* __restrict__ row,
                                                  const int* __restrict__ col,
                                                  const float* __restrict__ ew,
                                                  const unsigned* __restrict__ blkcur,
                                                  uint2* __restrict__ rec, int e) {
    __shared__ unsigned cur[MAXBINS];
    int B = blockIdx.x, tid = threadIdx.x;
    int chunk = (e + NB_CSR - 1) / NB_CSR;
    int beg = B * chunk, end = min(e, beg + chunk);
    if (tid < MAXBINS) cur[tid] = blkcur[B * MAXBINS + tid];
    __syncthreads();
    for (int i = beg + tid; i < end; i += 1024) {
        int c = col[i];
        unsigned slot = atomicAdd(&cur[c >> 8], 1u);
        rec[slot] = make_uint2((unsigned)row[i] | ((unsigned)(c & 255) << 20),
                               __float_as_uint(ew[i]));
    }
}

// ---- CSR pass 4 (1 block per bin): node hist + ptr slice + fused deg/dis +
//      final placement into the bin's contiguous edg window (L2-local) ----
__global__ __launch_bounds__(1024) void csr_k(const uint2* __restrict__ rec,
                                              const int* __restrict__ binbase,
                                              int* __restrict__ ptr,
                                              uint2* __restrict__ edg,
                                              float* __restrict__ dis, int n) {
    __shared__ unsigned ncnt[256];
    __shared__ unsigned nbase[256];
    __shared__ float degs[256];
    int b = blockIdx.x, tid = threadIdx.x;
    int beg = binbase[b], end = binbase[b + 1];
    int node0 = b << 8;
    int nn = min(256, n - node0);
    if (tid < 256) { ncnt[tid] = 0; degs[tid] = 0.f; }
    __syncthreads();
    for (int i = beg + tid; i < end; i += 1024) {
        uint2 r = rec[i];
        unsigned c8 = r.x >> 20;
        atomicAdd(&ncnt[c8], 1u);
        atomicAdd(&degs[c8], __uint_as_float(r.y));
    }
    __syncthreads();
    if (tid == 0) {
        unsigned run = (unsigned)beg;
        for (int k = 0; k < 256; ++k) { nbase[k] = run; run += ncnt[k]; }
    }
    __syncthreads();
    if (tid < nn) {
        ptr[node0 + tid] = (int)nbase[tid];
        dis[node0 + tid] = rsqrtf(degs[tid] + 2.0f);
    }
    if (tid < 256) ncnt[tid] = 0;
    __syncthreads();
    for (int i = beg + tid; i < end; i += 1024) {
        uint2 r = rec[i];
        unsigned c8 = r.x >> 20;
        unsigned pos = nbase[c8] + atomicAdd(&ncnt[c8], 1u);
        edg[pos] = make_uint2(r.x & 0xFFFFFu, r.y);
    }
}

// edg.y <- w * dis[src]  (fold source-side norm in once, for all layers)
__global__ __launch_bounds__(256) void normw_k(uint2* __restrict__ edg,
                                               const float* __restrict__ dis, int e) {
    int i = blockIdx.x * 256 + threadIdx.x;
    if (i >= e) return;
    uint2 ev = edg[i];
    ((unsigned*)edg)[2 * i + 1] =
        __float_as_uint(__uint_as_float(ev.y) * dis[ev.x]);
}

// Pack W (all L layers) into MFMA B-fragment layout, bf16 hi/lo split.
__global__ __launch_bounds__(256) void pack_k(const float* __restrict__ Ws,
                                              short* __restrict__ wpk, int L) {
    int ent = blockIdx.x * 256 + threadIdx.x;
    if (ent >= L * 512) return;
    int layer = ent >> 9;
    int r = ent & 511;
    int lane = r & 63;
    int st = r >> 6;
    int s = st >> 2, t = st & 3;
    int quad = lane >> 4;
    int ncol = t * 16 + (lane & 15);
    const float* W = Ws + (size_t)layer * DCH * DCH;
    union { short sh[8]; int4 v; } hi, lo;
#pragma unroll
    for (int j = 0; j < 8; ++j) {
        int k = s * 32 + quad * 8 + j;
        float w = W[k * DCH + ncol];
        unsigned short h = f2bf(w);
        hi.sh[j] = (short)h;
        lo.sh[j] = (short)f2bf(w - bf2f(h));
    }
    *(int4*)(wpk + ((size_t)(layer * 2 + 0) * 512 + r) * 8) = hi.v;
    *(int4*)(wpk + ((size_t)(layer * 2 + 1) * 512 + r) * 8) = lo.v;
}

// layer-0 GEMM: h = x0 @ W0 via bf16-split MFMA; output bf16.
__global__ __launch_bounds__(256) void gemm_k(const float* __restrict__ x,
                                              const short* __restrict__ wpk_layer,
                                              unsigned short* __restrict__ hb, int n_tiles) {
    __shared__ short Wl[2][512 * 8];
    {
        const int4* src = (const int4*)wpk_layer;
        int4* dst = (int4*)&Wl[0][0];
        for (int i = threadIdx.x; i < 1024; i += 256) dst[i] = src[i];
    }
    __syncthreads();
    int wave = threadIdx.x >> 6, lane = threadIdx.x & 63;
    int tile = blockIdx.x * 4 + wave;
    if (tile >= n_tiles) return;
    int m = lane & 15, quad = lane >> 4;
    int row = tile * 16 + m;

    float av[2][8];
    {
        const float4* p0 = (const float4*)(x + (size_t)row * DCH + quad * 8);
        const float4* p1 = (const float4*)(x + (size_t)row * DCH + 32 + quad * 8);
        float4 a0 = p0[0], a1 = p0[1], b0 = p1[0], b1 = p1[1];
        av[0][0] = a0.x; av[0][1] = a0.y; av[0][2] = a0.z; av[0][3] = a0.w;
        av[0][4] = a1.x; av[0][5] = a1.y; av[0][6] = a1.z; av[0][7] = a1.w;
        av[1][0] = b0.x; av[1][1] = b0.y; av[1][2] = b0.z; av[1][3] = b0.w;
        av[1][4] = b1.x; av[1][5] = b1.y; av[1][6] = b1.z; av[1][7] = b1.w;
    }
    bfrag ah[2], al[2];
#pragma unroll
    for (int s = 0; s < 2; ++s)
#pragma unroll
        for (int j = 0; j < 8; ++j) {
            unsigned short hbv = f2bf(av[s][j]);
            ah[s][j] = (short)hbv;
            al[s][j] = (short)f2bf(av[s][j] - bf2f(hbv));
        }

#pragma unroll
    for (int t = 0; t < 4; ++t) {
        ffrag acc = {0.f, 0.f, 0.f, 0.f};
#pragma unroll
        for (int s = 0; s < 2; ++s) {
            bfrag wh = *(bfrag*)&Wl[0][((s * 4 + t) * 64 + lane) * 8];
            bfrag wl = *(bfrag*)&Wl[1][((s * 4 + t) * 64 + lane) * 8];
            acc = __builtin_amdgcn_mfma_f32_16x16x32_bf16(ah[s], wh, acc, 0, 0, 0);
            acc = __builtin_amdgcn_mfma_f32_16x16x32_bf16(al[s], wh, acc, 0, 0, 0);
            acc = __builtin_amdgcn_mfma_f32_16x16x32_bf16(ah[s], wl, acc, 0, 0, 0);
        }
        int colc = t * 16 + m;
#pragma unroll
        for (int r = 0; r < 4; ++r)
            hb[(size_t)(tile * 16 + quad * 4 + r) * DCH + colc] = f2bf(acc[r]);
    }
}

// gather core: lane = channel pair, 2 edges/step, 8-deep pipelined.
// 8 outstanding 4B loads per lane — max MLP for this latency-bound loop.
static __device__ __forceinline__ void gather_node(int node, int lane, int p, int hf,
                                                   float dis_c,
                                                   const int* __restrict__ ptr,
                                                   const uint2* __restrict__ edg,
                                                   const unsigned* __restrict__ hbf,
                                                   float& A0, float& A1) {
    float a0 = 0.f, a1 = 0.f;
    if (hf == 0) {                               // self-loop term
        unsigned sv = hbf[(size_t)node * 32 + p];
        a0 = 2.0f * dis_c * __uint_as_float(sv << 16);
        a1 = 2.0f * dis_c * __uint_as_float(sv & 0xffff0000u);
    }
    int beg = ptr[node], end = ptr[node + 1];
    for (int base = beg; base < end; base += 64) {
        int idx = base + lane;
        int rv = 0; float nv = 0.f;
        if (idx < end) {
            uint2 ev = edg[idx];
            rv = (int)ev.x;
            nv = __uint_as_float(ev.y);          // pre-folded w * dis[src]
        }
        int m = min(64, end - base);
        int steps = (((m + 1) >> 1) + 7) & ~7;   // 2 edges/step, 8-deep pipelined
        for (int j0 = 0; j0 < steps; j0 += 8) {
            unsigned hv[8]; float nn[8];
#pragma unroll
            for (int q = 0; q < 8; ++q) {
                int eidx = 2 * (j0 + q) + hf;
                int r = __shfl(rv, eidx);
                nn[q] = __shfl(nv, eidx);
                hv[q] = hbf[(size_t)r * 32 + p];
            }
#pragma unroll
            for (int q = 0; q < 8; ++q) {
                a0 += __uint_as_float(hv[q] << 16) * nn[q];
                a1 += __uint_as_float(hv[q] & 0xffff0000u) * nn[q];
            }
        }
    }
    A0 = a0 + __shfl_xor(a0, 32);
    A1 = a1 + __shfl_xor(a1, 32);
}

// fused gather(l) + gemm(l+1): block = 4 waves = 16 nodes; activation tile in
// LDS (stride 68: 16B-aligned rows); wave t does MFMA col-group t.
__global__ __launch_bounds__(256) void gg_k(const int* __restrict__ ptr,
                                            const uint2* __restrict__ edg,
                                            const float* __restrict__ dis,
                                            const unsigned* __restrict__ hbf,
                                            const float* __restrict__ b,
                                            const short* __restrict__ wpk_next,
                                            unsigned short* __restrict__ hb_out, int n) {
    __shared__ float xs[16][68];
    int w = threadIdx.x >> 6, lane = threadIdx.x & 63;
    int p = lane & 31, hf = lane >> 5;
    int tile = blockIdx.x;
    float2 bv = ((const float2*)b)[p];
#pragma unroll 1
    for (int i = 0; i < 4; ++i) {
        int node = tile * 16 + w * 4 + i;
        if (node < n) {
            float dis_c = dis[node];
            float A0, A1;
            gather_node(node, lane, p, hf, dis_c, ptr, edg, hbf, A0, A1);
            if (hf == 0) {
                xs[w * 4 + i][2 * p]     = fmaxf(dis_c * A0 + bv.x, 0.f);
                xs[w * 4 + i][2 * p + 1] = fmaxf(dis_c * A1 + bv.y, 0.f);
            }
        }
    }
    __syncthreads();
    // ---- GEMM phase: wave w = output col-group t ----
    int m = lane & 15, quad = lane >> 4, t = w;
    bfrag ah[2], al[2];
#pragma unroll
    for (int s = 0; s < 2; ++s)
#pragma unroll
        for (int j = 0; j < 8; ++j) {
            float v = xs[m][s * 32 + quad * 8 + j];
            unsigned short hbv = f2bf(v);
            ah[s][j] = (short)hbv;
            al[s][j] = (short)f2bf(v - bf2f(hbv));
        }
    ffrag acc = {0.f, 0.f, 0.f, 0.f};
#pragma unroll
    for (int s = 0; s < 2; ++s) {
        bfrag wh = *(const bfrag*)(wpk_next + ((size_t)((s * 4 + t) * 64 + lane)) * 8);
        bfrag wl = *(const bfrag*)(wpk_next + ((size_t)(512 + (s * 4 + t) * 64 + lane)) * 8);
        acc = __builtin_amdgcn_mfma_f32_16x16x32_bf16(ah[s], wh, acc, 0, 0, 0);
        acc = __builtin_amdgcn_mfma_f32_16x16x32_bf16(al[s], wh, acc, 0, 0, 0);
        acc = __builtin_amdgcn_mfma_f32_16x16x32_bf16(ah[s], wl, acc, 0, 0, 0);
    }
    int colc = t * 16 + m;
#pragma unroll
    for (int r = 0; r < 4; ++r) {
        int orow = tile * 16 + quad * 4 + r;
        if (orow < n) hb_out[(size_t)orow * DCH + colc] = f2bf(acc[r]);
    }
}

// fused gather(last) + final dot: out[node] = relu-agg(node) . Wf + bf
__global__ __launch_bounds__(256) void gf_k(const int* __restrict__ ptr,
                                            const uint2* __restrict__ edg,
                                            const float* __restrict__ dis,
                                            const unsigned* __restrict__ hbf,
                                            const float* __restrict__ b,
                                            const float* __restrict__ Wf,
                                            const float* __restrict__ bf,
                                            float* __restrict__ out, int n) {
    int node = blockIdx.x * 4 + (threadIdx.x >> 6);
    int lane = threadIdx.x & 63;
    if (node >= n) return;
    int p = lane & 31, hf = lane >> 5;
    float dis_c = dis[node];
    float A0, A1;
    gather_node(node, lane, p, hf, dis_c, ptr, edg, hbf, A0, A1);
    float2 bv = ((const float2*)b)[p];
    float2 wv = ((const float2*)Wf)[p];
    float x0 = fmaxf(dis_c * A0 + bv.x, 0.f);
    float x1 = fmaxf(dis_c * A1 + bv.y, 0.f);
    float v = x0 * wv.x + x1 * wv.y;             // valid in lanes 0..31
#pragma unroll
    for (int off = 16; off > 0; off >>= 1) v += __shfl_down(v, off);
    if (lane == 0) out[node] = v + bf[0];
}

extern "C" void kernel_launch(void* const* d_in, const int* in_sizes, int n_in,
                              void* d_out, int out_size, void* d_ws, size_t ws_size,
                              hipStream_t stream) {
    const float* x0 = (const float*)d_in[0];
    const int*   ei = (const int*)d_in[1];
    const float* ew = (const float*)d_in[2];
    const float* Ws = (const float*)d_in[3];
    const float* bs = (const float*)d_in[4];
    const float* Wf = (const float*)d_in[5];
    const float* bf = (const float*)d_in[6];

    const int n = in_sizes[0] / DCH;
    const int e = in_sizes[2];
    const int L = in_sizes[3] / (DCH * DCH);     // = 3

    const int* row = ei;        // edge_index[0] = source (gathered)
    const int* col = ei + e;    // edge_index[1] = target (aggregated)
    const int nbins = (n + 255) >> 8;            // 196 for n=50000 (must be <= 256)

    size_t off = 0;
    auto alloc = [&](size_t bytes) {
        off = (off + 255) & ~(size_t)255;
        void* r = (char*)d_ws + off;
        off += bytes;
        return r;
    };
    int*      ptr     = (int*)     alloc((size_t)(n + 1) * 4);
    float*    dis     = (float*)   alloc((size_t)n * 4);
    short*    wpk     = (short*)   alloc((size_t)L * 2 * 512 * 8 * 2);
    uint2*    edg     = (uint2*)   alloc((size_t)e * 8);
    unsigned* blkcnt  = (unsigned*)alloc((size_t)NB_CSR * MAXBINS * 4);
    unsigned* blkcur  = (unsigned*)alloc((size_t)NB_CSR * MAXBINS * 4);
    int*      binbase = (int*)     alloc((size_t)(MAXBINS + 1) * 4);
    // region A: rec (e uint2 = 10 MB) aliases TWO bf16 h buffers (12.8 MB);
    // rec is dead after csr_k, which precedes the first gemm write.
    size_t szR = (size_t)e * 8;
    size_t szH = (size_t)2 * n * DCH * 2;
    unsigned char* regA = (unsigned char*)alloc(szR > szH ? szR : szH);
    uint2* rec = (uint2*)regA;
    unsigned short* hb_a = (unsigned short*)regA;
    unsigned short* hb_b = hb_a + (size_t)n * DCH;

    dim3 blk(256);
    const int n_tiles = (n + 15) / 16;

    // ---- CSR build (bin sort) + norm + W pack ----
    binc_k   <<<dim3(NB_CSR), dim3(1024), 0, stream>>>(col, blkcnt, e);
    bincur_k <<<dim3(1), blk, 0, stream>>>(blkcnt, blkcur, binbase, ptr, nbins, n, e);
    binfill_k<<<dim3(NB_CSR), dim3(1024), 0, stream>>>(row, col, ew, blkcur, rec, e);
    csr_k    <<<dim3(nbins), dim3(1024), 0, stream>>>(rec, binbase, ptr, edg, dis, n);
    normw_k  <<<dim3((e + 255) / 256), blk, 0, stream>>>(edg, dis, e);
    pack_k   <<<dim3((L * 512 + 255) / 256), blk, 0, stream>>>(Ws, wpk, L);

    // ---- layers (fused) ----
    const size_t wstride = (size_t)2 * 512 * 8;
    gemm_k<<<dim3((n_tiles + 3) / 4), blk, 0, stream>>>(x0, wpk, hb_a, n_tiles);
    gg_k  <<<dim3(n_tiles), blk, 0, stream>>>(ptr, edg, dis, (const unsigned*)hb_a,
                                              bs, wpk + wstride, hb_b, n);
    gg_k  <<<dim3(n_tiles), blk, 0, stream>>>(ptr, edg, dis, (const unsigned*)hb_b,
                                              bs + DCH, wpk + 2 * wstride, hb_a, n);
    gf_k  <<<dim3((n + 3) / 4), blk, 0, stream>>>(ptr, edg, dis, (const unsigned*)hb_a,
                                                  bs + 2 * DCH, Wf, bf, (float*)d_out, n);
}

// Round 14
// 220.799 us; speedup vs baseline: 1.2836x; 1.0068x over previous
//
#include <hip/hip_runtime.h>
#include <hip/hip_bf16.h>

#define DCH 64
#define NB_CSR 256          // edge-chunk blocks; chunk = ceil(e/256)
#define MAXBINS 256         // bins = ceil(n/256); n<=65536

typedef __attribute__((ext_vector_type(8))) short bfrag;   // 8 bf16
typedef __attribute__((ext_vector_type(4))) float ffrag;   // 4 fp32

static __device__ __forceinline__ unsigned short f2bf(float f) {
    unsigned u = __float_as_uint(f);
    unsigned r = (u + 0x7fffu + ((u >> 16) & 1u)) >> 16;   // RNE
    return (unsigned short)r;
}
static __device__ __forceinline__ float bf2f(unsigned short s) {
    return __uint_as_float(((unsigned)s) << 16);
}

// ---- CSR pass 1: per-block bin counts (bin = col>>8) ----
__global__ __launch_bounds__(1024) void binc_k(const int* __restrict__ col,
                                               unsigned* __restrict__ blkcnt, int e) {
    __shared__ unsigned bins[MAXBINS];
    int B = blockIdx.x, tid = threadIdx.x;
    int chunk = (e + NB_CSR - 1) / NB_CSR;
    int beg = B * chunk, end = min(e, beg + chunk);
    if (tid < MAXBINS) bins[tid] = 0;
    __syncthreads();
    for (int i = beg + tid; i < end; i += 1024)
        atomicAdd(&bins[col[i] >> 8], 1u);
    __syncthreads();
    if (tid < MAXBINS) blkcnt[B * MAXBINS + tid] = bins[tid];
}

// ---- CSR pass 2a (1 wave per bin): column prefix over the 256 chunk counts.
// blkcur[B][j] = exclusive prefix WITHIN bin j (base added later in binfill).
__global__ __launch_bounds__(64) void bincur1_k(const unsigned* __restrict__ blkcnt,
                                                unsigned* __restrict__ blkcur,
                                                unsigned* __restrict__ tot) {
    int j = blockIdx.x, lane = threadIdx.x;
    unsigned carry = 0;
#pragma unroll
    for (int c = 0; c < NB_CSR; c += 64) {
        unsigned v = blkcnt[(size_t)(c + lane) * MAXBINS + j];
        unsigned s = v;
#pragma unroll
        for (int off = 1; off < 64; off <<= 1) {
            unsigned t = __shfl_up(s, off);
            if (lane >= off) s += t;
        }
        blkcur[(size_t)(c + lane) * MAXBINS + j] = carry + s - v;
        carry += __shfl(s, 63);
    }
    if (lane == 0) tot[j] = carry;
}

// ---- CSR pass 2b (1 block): exclusive scan of bin totals -> binbase ----
__global__ __launch_bounds__(256) void bincur2_k(const unsigned* __restrict__ tot,
                                                 int* __restrict__ binbase,
                                                 int* __restrict__ ptr,
                                                 int nbins, int n, int e) {
    __shared__ int wtot[4];
    int tid = threadIdx.x, lane = tid & 63, w = tid >> 6;
    int v = (tid < nbins) ? (int)tot[tid] : 0;
    int s = v;
#pragma unroll
    for (int off = 1; off < 64; off <<= 1) {
        int t = __shfl_up(s, off);
        if (lane >= off) s += t;
    }
    if (lane == 63) wtot[w] = s;
    __syncthreads();
    if (tid == 0) {
        int r = 0;
#pragma unroll
        for (int k = 0; k < 4; ++k) { int t = wtot[k]; wtot[k] = r; r += t; }
    }
    __syncthreads();
    int excl = s - v + wtot[w];
    if (tid < nbins) binbase[tid] = excl;
    if (tid == 0) { binbase[nbins] = e; ptr[n] = e; }
}

// ---- CSR pass 3: scatter packed records to bins (runs at block cursors) ----
__global__ __launch_bounds__(1024) void binfill_k(const int* __restrict__ row,
                                                  const int* __restrict__ col,
                                                  const float* __restrict__ ew,
                                                  const unsigned* __restrict__ blkcur,
                                                  const int* __restrict__ binbase,
                                                  uint2* __restrict__ rec, int e) {
    __shared__ unsigned cur[MAXBINS];
    int B = blockIdx.x, tid = threadIdx.x;
    int chunk = (e + NB_CSR - 1) / NB_CSR;
    int beg = B * chunk, end = min(e, beg + chunk);
    if (tid < MAXBINS) cur[tid] = blkcur[(size_t)B * MAXBINS + tid]
                                + (unsigned)binbase[tid];
    __syncthreads();
    for (int i = beg + tid; i < end; i += 1024) {
        int c = col[i];
        unsigned slot = atomicAdd(&cur[c >> 8], 1u);
        rec[slot] = make_uint2((unsigned)row[i] | ((unsigned)(c & 255) << 20),
                               __float_as_uint(ew[i]));
    }
}

// ---- CSR pass 4 (1 block per bin): node hist + ptr slice + fused deg/dis +
//      final placement into the bin's contiguous edg window (L2-local) ----
__global__ __launch_bounds__(1024) void csr_k(const uint2* __restrict__ rec,
                                              const int* __restrict__ binbase,
                                              int* __restrict__ ptr,
                                              uint2* __restrict__ edg,
                                              float* __restrict__ dis, int n) {
    __shared__ unsigned ncnt[256];
    __shared__ unsigned nbase[256];
    __shared__ float degs[256];
    int b = blockIdx.x, tid = threadIdx.x;
    int beg = binbase[b], end = binbase[b + 1];
    int node0 = b << 8;
    int nn = min(256, n - node0);
    if (tid < 256) { ncnt[tid] = 0; degs[tid] = 0.f; }
    __syncthreads();
    for (int i = beg + tid; i < end; i += 1024) {
        uint2 r = rec[i];
        unsigned c8 = r.x >> 20;
        atomicAdd(&ncnt[c8], 1u);
        atomicAdd(&degs[c8], __uint_as_float(r.y));
    }
    __syncthreads();
    if (tid == 0) {
        unsigned run = (unsigned)beg;
        for (int k = 0; k < 256; ++k) { nbase[k] = run; run += ncnt[k]; }
    }
    __syncthreads();
    if (tid < nn) {
        ptr[node0 + tid] = (int)nbase[tid];
        dis[node0 + tid] = rsqrtf(degs[tid] + 2.0f);
    }
    if (tid < 256) ncnt[tid] = 0;
    __syncthreads();
    for (int i = beg + tid; i < end; i += 1024) {
        uint2 r = rec[i];
        unsigned c8 = r.x >> 20;
        unsigned pos = nbase[c8] + atomicAdd(&ncnt[c8], 1u);
        edg[pos] = make_uint2(r.x & 0xFFFFFu, r.y);
    }
}

// edg.y <- w * dis[src]  (fold source-side norm in once, for all layers)
__global__ __launch_bounds__(256) void normw_k(uint2* __restrict__ edg,
                                               const float* __restrict__ dis, int e) {
    int i = blockIdx.x * 256 + threadIdx.x;
    if (i >= e) return;
    uint2 ev = edg[i];
    ((unsigned*)edg)[2 * i + 1] =
        __float_as_uint(__uint_as_float(ev.y) * dis[ev.x]);
}

// Pack W (all L layers) into MFMA B-fragment layout, bf16 hi/lo split.
__global__ __launch_bounds__(256) void pack_k(const float* __restrict__ Ws,
                                              short* __restrict__ wpk, int L) {
    int ent = blockIdx.x * 256 + threadIdx.x;
    if (ent >= L * 512) return;
    int layer = ent >> 9;
    int r = ent & 511;
    int lane = r & 63;
    int st = r >> 6;
    int s = st >> 2, t = st & 3;
    int quad = lane >> 4;
    int ncol = t * 16 + (lane & 15);
    const float* W = Ws + (size_t)layer * DCH * DCH;
    union { short sh[8]; int4 v; } hi, lo;
#pragma unroll
    for (int j = 0; j < 8; ++j) {
        int k = s * 32 + quad * 8 + j;
        float w = W[k * DCH + ncol];
        unsigned short h = f2bf(w);
        hi.sh[j] = (short)h;
        lo.sh[j] = (short)f2bf(w - bf2f(h));
    }
    *(int4*)(wpk + ((size_t)(layer * 2 + 0) * 512 + r) * 8) = hi.v;
    *(int4*)(wpk + ((size_t)(layer * 2 + 1) * 512 + r) * 8) = lo.v;
}

// layer-0 GEMM: h = x0 @ W0 via bf16-split MFMA; output bf16.
__global__ __launch_bounds__(256) void gemm_k(const float* __restrict__ x,
                                              const short* __restrict__ wpk_layer,
                                              unsigned short* __restrict__ hb, int n_tiles) {
    __shared__ short Wl[2][512 * 8];
    {
        const int4* src = (const int4*)wpk_layer;
        int4* dst = (int4*)&Wl[0][0];
        for (int i = threadIdx.x; i < 1024; i += 256) dst[i] = src[i];
    }
    __syncthreads();
    int wave = threadIdx.x >> 6, lane = threadIdx.x & 63;
    int tile = blockIdx.x * 4 + wave;
    if (tile >= n_tiles) return;
    int m = lane & 15, quad = lane >> 4;
    int row = tile * 16 + m;

    float av[2][8];
    {
        const float4* p0 = (const float4*)(x + (size_t)row * DCH + quad * 8);
        const float4* p1 = (const float4*)(x + (size_t)row * DCH + 32 + quad * 8);
        float4 a0 = p0[0], a1 = p0[1], b0 = p1[0], b1 = p1[1];
        av[0][0] = a0.x; av[0][1] = a0.y; av[0][2] = a0.z; av[0][3] = a0.w;
        av[0][4] = a1.x; av[0][5] = a1.y; av[0][6] = a1.z; av[0][7] = a1.w;
        av[1][0] = b0.x; av[1][1] = b0.y; av[1][2] = b0.z; av[1][3] = b0.w;
        av[1][4] = b1.x; av[1][5] = b1.y; av[1][6] = b1.z; av[1][7] = b1.w;
    }
    bfrag ah[2], al[2];
#pragma unroll
    for (int s = 0; s < 2; ++s)
#pragma unroll
        for (int j = 0; j < 8; ++j) {
            unsigned short hbv = f2bf(av[s][j]);
            ah[s][j] = (short)hbv;
            al[s][j] = (short)f2bf(av[s][j] - bf2f(hbv));
        }

#pragma unroll
    for (int t = 0; t < 4; ++t) {
        ffrag acc = {0.f, 0.f, 0.f, 0.f};
#pragma unroll
        for (int s = 0; s < 2; ++s) {
            bfrag wh = *(bfrag*)&Wl[0][((s * 4 + t) * 64 + lane) * 8];
            bfrag wl = *(bfrag*)&Wl[1][((s * 4 + t) * 64 + lane) * 8];
            acc = __builtin_amdgcn_mfma_f32_16x16x32_bf16(ah[s], wh, acc, 0, 0, 0);
            acc = __builtin_amdgcn_mfma_f32_16x16x32_bf16(al[s], wh, acc, 0, 0, 0);
            acc = __builtin_amdgcn_mfma_f32_16x16x32_bf16(ah[s], wl, acc, 0, 0, 0);
        }
        int colc = t * 16 + m;
#pragma unroll
        for (int r = 0; r < 4; ++r)
            hb[(size_t)(tile * 16 + quad * 4 + r) * DCH + colc] = f2bf(acc[r]);
    }
}

// gather core: lane = channel pair, 2 edges/step, 16-deep pipelined.
// 16 outstanding 4B loads per lane (avg degree 25 -> ceil(13)->16 steps pads
// identically to the 8-deep version, but issues as ONE group: 2x MLP).
static __device__ __forceinline__ void gather_node(int node, int lane, int p, int hf,
                                                   float dis_c,
                                                   const int* __restrict__ ptr,
                                                   const uint2* __restrict__ edg,
                                                   const unsigned* __restrict__ hbf,
                                                   float& A0, float& A1) {
    float a0 = 0.f, a1 = 0.f;
    if (hf == 0) {                               // self-loop term
        unsigned sv = hbf[(size_t)node * 32 + p];
        a0 = 2.0f * dis_c * __uint_as_float(sv << 16);
        a1 = 2.0f * dis_c * __uint_as_float(sv & 0xffff0000u);
    }
    int beg = ptr[node], end = ptr[node + 1];
    for (int base = beg; base < end; base += 64) {
        int idx = base + lane;
        int rv = 0; float nv = 0.f;
        if (idx < end) {
            uint2 ev = edg[idx];
            rv = (int)ev.x;
            nv = __uint_as_float(ev.y);          // pre-folded w * dis[src]
        }
        int m = min(64, end - base);
        int steps = (((m + 1) >> 1) + 15) & ~15; // 2 edges/step, 16-deep pipelined
        for (int j0 = 0; j0 < steps; j0 += 16) {
            unsigned hv[16]; float nn[16];
#pragma unroll
            for (int q = 0; q < 16; ++q) {
                int eidx = 2 * (j0 + q) + hf;
                int r = __shfl(rv, eidx);
                nn[q] = __shfl(nv, eidx);        // padded lanes carry nv=0
                hv[q] = hbf[(size_t)r * 32 + p];
            }
#pragma unroll
            for (int q = 0; q < 16; ++q) {
                a0 += __uint_as_float(hv[q] << 16) * nn[q];
                a1 += __uint_as_float(hv[q] & 0xffff0000u) * nn[q];
            }
        }
    }
    A0 = a0 + __shfl_xor(a0, 32);
    A1 = a1 + __shfl_xor(a1, 32);
}

// fused gather(l) + gemm(l+1): block = 4 waves = 16 nodes; activation tile in
// LDS (stride 68: 16B-aligned rows); wave t does MFMA col-group t.
__global__ __launch_bounds__(256) void gg_k(const int* __restrict__ ptr,
                                            const uint2* __restrict__ edg,
                                            const float* __restrict__ dis,
                                            const unsigned* __restrict__ hbf,
                                            const float* __restrict__ b,
                                            const short* __restrict__ wpk_next,
                                            unsigned short* __restrict__ hb_out, int n) {
    __shared__ float xs[16][68];
    int w = threadIdx.x >> 6, lane = threadIdx.x & 63;
    int p = lane & 31, hf = lane >> 5;
    int tile = blockIdx.x;
    float2 bv = ((const float2*)b)[p];
#pragma unroll 1
    for (int i = 0; i < 4; ++i) {
        int node = tile * 16 + w * 4 + i;
        if (node < n) {
            float dis_c = dis[node];
            float A0, A1;
            gather_node(node, lane, p, hf, dis_c, ptr, edg, hbf, A0, A1);
            if (hf == 0) {
                xs[w * 4 + i][2 * p]     = fmaxf(dis_c * A0 + bv.x, 0.f);
                xs[w * 4 + i][2 * p + 1] = fmaxf(dis_c * A1 + bv.y, 0.f);
            }
        }
    }
    __syncthreads();
    // ---- GEMM phase: wave w = output col-group t ----
    int m = lane & 15, quad = lane >> 4, t = w;
    bfrag ah[2], al[2];
#pragma unroll
    for (int s = 0; s < 2; ++s)
#pragma unroll
        for (int j = 0; j < 8; ++j) {
            float v = xs[m][s * 32 + quad * 8 + j];
            unsigned short hbv = f2bf(v);
            ah[s][j] = (short)hbv;
            al[s][j] = (short)f2bf(v - bf2f(hbv));
        }
    ffrag acc = {0.f, 0.f, 0.f, 0.f};
#pragma unroll
    for (int s = 0; s < 2; ++s) {
        bfrag wh = *(const bfrag*)(wpk_next + ((size_t)((s * 4 + t) * 64 + lane)) * 8);
        bfrag wl = *(const bfrag*)(wpk_next + ((size_t)(512 + (s * 4 + t) * 64 + lane)) * 8);
        acc = __builtin_amdgcn_mfma_f32_16x16x32_bf16(ah[s], wh, acc, 0, 0, 0);
        acc = __builtin_amdgcn_mfma_f32_16x16x32_bf16(al[s], wh, acc, 0, 0, 0);
        acc = __builtin_amdgcn_mfma_f32_16x16x32_bf16(ah[s], wl, acc, 0, 0, 0);
    }
    int colc = t * 16 + m;
#pragma unroll
    for (int r = 0; r < 4; ++r) {
        int orow = tile * 16 + quad * 4 + r;
        if (orow < n) hb_out[(size_t)orow * DCH + colc] = f2bf(acc[r]);
    }
}

// fused gather(last) + final dot: out[node] = relu-agg(node) . Wf + bf
__global__ __launch_bounds__(256) void gf_k(const int* __restrict__ ptr,
                                            const uint2* __restrict__ edg,
                                            const float* __restrict__ dis,
                                            const unsigned* __restrict__ hbf,
                                            const float* __restrict__ b,
                                            const float* __restrict__ Wf,
                                            const float* __restrict__ bf,
                                            float* __restrict__ out, int n) {
    int node = blockIdx.x * 4 + (threadIdx.x >> 6);
    int lane = threadIdx.x & 63;
    if (node >= n) return;
    int p = lane & 31, hf = lane >> 5;
    float dis_c = dis[node];
    float A0, A1;
    gather_node(node, lane, p, hf, dis_c, ptr, edg, hbf, A0, A1);
    float2 bv = ((const float2*)b)[p];
    float2 wv = ((const float2*)Wf)[p];
    float x0 = fmaxf(dis_c * A0 + bv.x, 0.f);
    float x1 = fmaxf(dis_c * A1 + bv.y, 0.f);
    float v = x0 * wv.x + x1 * wv.y;             // valid in lanes 0..31
#pragma unroll
    for (int off = 16; off > 0; off >>= 1) v += __shfl_down(v, off);
    if (lane == 0) out[node] = v + bf[0];
}

extern "C" void kernel_launch(void* const* d_in, const int* in_sizes, int n_in,
                              void* d_out, int out_size, void* d_ws, size_t ws_size,
                              hipStream_t stream) {
    const float* x0 = (const float*)d_in[0];
    const int*   ei = (const int*)d_in[1];
    const float* ew = (const float*)d_in[2];
    const float* Ws = (const float*)d_in[3];
    const float* bs = (const float*)d_in[4];
    const float* Wf = (const float*)d_in[5];
    const float* bf = (const float*)d_in[6];

    const int n = in_sizes[0] / DCH;
    const int e = in_sizes[2];
    const int L = in_sizes[3] / (DCH * DCH);     // = 3

    const int* row = ei;        // edge_index[0] = source (gathered)
    const int* col = ei + e;    // edge_index[1] = target (aggregated)
    const int nbins = (n + 255) >> 8;            // 196 for n=50000 (must be <= 256)

    size_t off = 0;
    auto alloc = [&](size_t bytes) {
        off = (off + 255) & ~(size_t)255;
        void* r = (char*)d_ws + off;
        off += bytes;
        return r;
    };
    int*      ptr     = (int*)     alloc((size_t)(n + 1) * 4);
    float*    dis     = (float*)   alloc((size_t)n * 4);
    short*    wpk     = (short*)   alloc((size_t)L * 2 * 512 * 8 * 2);
    uint2*    edg     = (uint2*)   alloc((size_t)e * 8);
    unsigned* blkcnt  = (unsigned*)alloc((size_t)NB_CSR * MAXBINS * 4);
    unsigned* blkcur  = (unsigned*)alloc((size_t)NB_CSR * MAXBINS * 4);
    unsigned* tot     = (unsigned*)alloc((size_t)MAXBINS * 4);
    int*      binbase = (int*)     alloc((size_t)(MAXBINS + 1) * 4);
    // region A: rec (e uint2 = 10 MB) aliases TWO bf16 h buffers (12.8 MB);
    // rec is dead after csr_k, which precedes the first gemm write.
    size_t szR = (size_t)e * 8;
    size_t szH = (size_t)2 * n * DCH * 2;
    unsigned char* regA = (unsigned char*)alloc(szR > szH ? szR : szH);
    uint2* rec = (uint2*)regA;
    unsigned short* hb_a = (unsigned short*)regA;
    unsigned short* hb_b = hb_a + (size_t)n * DCH;

    dim3 blk(256);
    const int n_tiles = (n + 15) / 16;

    // ---- CSR build (bin sort) + norm + W pack ----
    binc_k   <<<dim3(NB_CSR), dim3(1024), 0, stream>>>(col, blkcnt, e);
    bincur1_k<<<dim3(nbins), dim3(64), 0, stream>>>(blkcnt, blkcur, tot);
    bincur2_k<<<dim3(1), blk, 0, stream>>>(tot, binbase, ptr, nbins, n, e);
    binfill_k<<<dim3(NB_CSR), dim3(1024), 0, stream>>>(row, col, ew, blkcur, binbase, rec, e);
    csr_k    <<<dim3(nbins), dim3(1024), 0, stream>>>(rec, binbase, ptr, edg, dis, n);
    normw_k  <<<dim3((e + 255) / 256), blk, 0, stream>>>(edg, dis, e);
    pack_k   <<<dim3((L * 512 + 255) / 256), blk, 0, stream>>>(Ws, wpk, L);

    // ---- layers (fused) ----
    const size_t wstride = (size_t)2 * 512 * 8;
    gemm_k<<<dim3((n_tiles + 3) / 4), blk, 0, stream>>>(x0, wpk, hb_a, n_tiles);
    gg_k  <<<dim3(n_tiles), blk, 0, stream>>>(ptr, edg, dis, (const unsigned*)hb_a,
                                              bs, wpk + wstride, hb_b, n);
    gg_k  <<<dim3(n_tiles), blk, 0, stream>>>(ptr, edg, dis, (const unsigned*)hb_b,
                                              bs + DCH, wpk + 2 * wstride, hb_a, n);
    gf_k  <<<dim3((n + 3) / 4), blk, 0, stream>>>(ptr, edg, dis, (const unsigned*)hb_a,
                                                  bs + 2 * DCH, Wf, bf, (float*)d_out, n);
}